// Round 2
// baseline (192.422 us; speedup 1.0000x reference)
//
#include <hip/hip_runtime.h>

// LowRankSig_HigherOrder: B=32, T=2048, F=64 (time + 63), K=10 tensors, U=64 units.
// Affine-scan decomposition. Each wave (64 lanes = 64 units) handles an 8-row
// sub-chunk: computes its M tile on the fly (fp32 dot products, x broadcast
// from LDS, kernel weights streamed from L2), scans with zero init state, and
// produces a 17-parameter affine map of the carried state (c1,c3,cA,c6,cP,cQ):
//   q0  o   : local out                q1..q6  a_*: d(out)/d(c_in)
//   q7..q12 d_*: state increments      q13 tA3, q14 tP6, q15 tQP, q16 tQ6
// The two 8-row maps in a workgroup are composed in LDS into one 16-row map
// (the family is closed under composition), keeping ws at 32*128*17*64*4 =
// 17.8 MB. A tiny second kernel folds the 128 maps sequentially per (b,u).

#define TT 2048
#define NFX 63
#define KT 10
#define NU 64
#define NQ 17
#define NCC 128      // 16-row chunks per batch (ws layout)
#define TSTRIDE 20   // padded row stride (floats) for XaT [f][row], 17 rows used

enum {Qo=0, Qa1, Qa3, QaA, Qa6, QaP, QaQ, Qd1, Qd3, QdA, Qd6, QdP, QdQ,
      QtA3, QtP6, QtQP, QtQ6};

template<int KP>
__device__ __forceinline__ void compute_m9(
    const float* __restrict__ Kw, const float* __restrict__ XaT,
    int rowbase, int u, int kbase, float (&acc)[9][KP])
{
#pragma unroll
  for (int r = 0; r < 9; ++r)
#pragma unroll
    for (int k = 0; k < KP; ++k) acc[r][k] = 0.f;

  for (int f = 0; f < 64; ++f) {
    const float* xb = &XaT[f * TSTRIDE + rowbase];
    float xr[9];
    float4 v0 = *reinterpret_cast<const float4*>(xb);
    float4 v1 = *reinterpret_cast<const float4*>(xb + 4);
    xr[0]=v0.x; xr[1]=v0.y; xr[2]=v0.z; xr[3]=v0.w;
    xr[4]=v1.x; xr[5]=v1.y; xr[6]=v1.z; xr[7]=v1.w;
    xr[8]=xb[8];
    const float* kp = &Kw[f * (KT*NU) + kbase * NU + u];
#pragma unroll
    for (int k = 0; k < KP; ++k) {
      float kv = kp[k * NU];
#pragma unroll
      for (int r = 0; r < 9; ++r)
        acc[r][k] = fmaf(xr[r], kv, acc[r][k]);
    }
  }
}

__global__ __launch_bounds__(128, 5)
void lrsig_chunk_kernel(const float* __restrict__ X,
                        const float* __restrict__ Kw,
                        float* __restrict__ ws)
{
  // smem holds the Xa tile (64*TSTRIDE = 1280 floats) during compute, then is
  // reused (after a barrier) as the 2x17x64 composition buffer (2176 floats).
  __shared__ float smem[2 * NQ * NU];

  const int b = blockIdx.y;
  const int cc = blockIdx.x;         // 0..127, 16 rows per WG
  const int tid = threadIdx.x;
  const int u = tid & 63;
  const int w = tid >> 6;            // wave 0/1, rows [8w, 8w+8)
  const int t0 = cc * 16;

  // ---- load Xa tile rows t0-1 .. t0+15, transposed [f][row] ----
  for (int idx = tid; idx < 17 * NFX; idx += 128) {
    int row = idx / NFX;
    int col = idx - row * NFX;
    int gt = t0 - 1 + row; if (gt < 0) gt = 0;   // dup row 0 -> diff 0 at t=0
    smem[(col + 1) * TSTRIDE + row] = X[((size_t)b * TT + gt) * NFX + col];
  }
  if (tid < 17) {
    int gt = t0 - 1 + tid; if (gt < 0) gt = 0;
    smem[tid] = (float)gt * (2.0f / 2047.0f) - 1.0f;  // time feature f=0
  }
  __syncthreads();

  const int rowbase = 8 * w;
  float outq[NQ];

  // ---------- phase A: k = 0,1,2 ----------
  {
    float acc[9][3];
    compute_m9<3>(Kw, smem, rowbase, u, 0, acc);
    float oA = 0.f, a1 = 0.f, lc1 = 0.f;
#pragma unroll
    for (int t = 0; t < 8; ++t) {
      float m0 = acc[t+1][0] - acc[t][0];
      float m1 = acc[t+1][1] - acc[t][1];
      float m2 = acc[t+1][2] - acc[t][2];
      oA += m0 + m2 * (lc1 + 0.5f * m1);
      a1 += m2;
      lc1 += m1;
    }
    outq[Qo] = oA; outq[Qa1] = a1; outq[Qd1] = lc1;
  }

  // ---------- phase B: k = 3,4,5 ----------
  {
    float acc[9][3];
    compute_m9<3>(Kw, smem, rowbase, u, 3, acc);
    float oB = 0.f, a3 = 0.f, aA = 0.f;
    float lc3 = 0.f, lcA = 0.f, g4 = 0.f;
#pragma unroll
    for (int t = 0; t < 8; ++t) {
      float m3 = acc[t+1][0] - acc[t][0];
      float m4 = acc[t+1][1] - acc[t][1];
      float m5 = acc[t+1][2] - acc[t][2];
      float s0 = m4 * lc3;
      float s1 = 0.5f * m4 * m3;
      oB += m5 * (lcA + 0.5f * s0 + (1.f/3.f) * s1);
      a3 += m5 * (g4 + 0.5f * m4);
      aA += m5;
      lcA += s0 + s1;
      g4  += m4;
      lc3 += m3;
    }
    outq[Qo] += oB;
    outq[Qa3] = a3; outq[QaA] = aA; outq[Qd3] = lc3; outq[QdA] = lcA;
    outq[QtA3] = g4;
  }

  // ---------- phase C: k = 6,7,8,9 ----------
  {
    float acc[9][4];
    compute_m9<4>(Kw, smem, rowbase, u, 6, acc);
    float oC = 0.f, a6 = 0.f, aP = 0.f, aQ = 0.f;
    float lc6 = 0.f, lcP = 0.f, lcQ = 0.f, g7 = 0.f, g8 = 0.f, h = 0.f;
#pragma unroll
    for (int t = 0; t < 8; ++t) {
      float m6 = acc[t+1][0] - acc[t][0];
      float m7 = acc[t+1][1] - acc[t][1];
      float m8 = acc[t+1][2] - acc[t][2];
      float m9 = acc[t+1][3] - acc[t][3];
      float p0 = m7 * lc6;
      float p1 = 0.5f * m7 * m6;
      float q0 = m8 * lcP;
      float q1 = 0.5f * m8 * p0;
      float q2 = (1.f/3.f) * m8 * p1;
      oC += m9 * (lcQ + 0.5f * q0 + (1.f/3.f) * q1 + 0.25f * q2);
      a6 += m9 * (h + m8 * (0.5f * g7 + (1.f/6.f) * m7));
      aP += m9 * (g8 + 0.5f * m8);
      aQ += m9;
      h  += m8 * (g7 + 0.5f * m7);   // exclusive g7, before update
      lcP += p0 + p1;
      lcQ += q0 + q1 + q2;
      g7 += m7; g8 += m8; lc6 += m6;
    }
    outq[Qo] += oC;
    outq[Qa6] = a6; outq[QaP] = aP; outq[QaQ] = aQ;
    outq[Qd6] = lc6; outq[QdP] = lcP; outq[QdQ] = lcQ;
    outq[QtP6] = g7; outq[QtQP] = g8; outq[QtQ6] = h;
  }

  // ---- compose the two 8-row maps (wave0 = first half) in LDS ----
  __syncthreads();   // all XaT reads done; safe to reuse smem
  {
    float* p = &smem[(w * NQ) * NU + u];
#pragma unroll
    for (int q = 0; q < NQ; ++q) p[q * NU] = outq[q];
  }
  __syncthreads();

  if (tid < NU) {
    const int uu = tid;
    float q1v[NQ], q2v[NQ], r[NQ];
#pragma unroll
    for (int q = 0; q < NQ; ++q) {
      q1v[q] = smem[q * NU + uu];
      q2v[q] = smem[(NQ + q) * NU + uu];
    }
    r[Qo]  = q1v[Qo] + q2v[Qo]
           + q2v[Qa1]*q1v[Qd1] + q2v[Qa3]*q1v[Qd3] + q2v[QaA]*q1v[QdA]
           + q2v[Qa6]*q1v[Qd6] + q2v[QaP]*q1v[QdP] + q2v[QaQ]*q1v[QdQ];
    r[Qa1] = q1v[Qa1] + q2v[Qa1];
    r[Qa3] = q1v[Qa3] + q2v[Qa3] + q1v[QtA3]*q2v[QaA];
    r[QaA] = q1v[QaA] + q2v[QaA];
    r[Qa6] = q1v[Qa6] + q2v[Qa6] + q1v[QtP6]*q2v[QaP] + q1v[QtQ6]*q2v[QaQ];
    r[QaP] = q1v[QaP] + q2v[QaP] + q1v[QtQP]*q2v[QaQ];
    r[QaQ] = q1v[QaQ] + q2v[QaQ];
    r[Qd1] = q1v[Qd1] + q2v[Qd1];
    r[Qd3] = q1v[Qd3] + q2v[Qd3];
    r[QdA] = q1v[QdA] + q2v[QdA] + q2v[QtA3]*q1v[Qd3];
    r[Qd6] = q1v[Qd6] + q2v[Qd6];
    r[QdP] = q1v[QdP] + q2v[QdP] + q2v[QtP6]*q1v[Qd6];
    r[QdQ] = q1v[QdQ] + q2v[QdQ] + q2v[QtQP]*q1v[QdP] + q2v[QtQ6]*q1v[Qd6];
    r[QtA3] = q1v[QtA3] + q2v[QtA3];
    r[QtP6] = q1v[QtP6] + q2v[QtP6];
    r[QtQP] = q1v[QtQP] + q2v[QtQP];
    r[QtQ6] = q1v[QtQ6] + q2v[QtQ6] + q2v[QtQP]*q1v[QtP6];

    float* p = &ws[(((size_t)b * NCC + cc) * NQ) * NU + uu];
#pragma unroll
    for (int q = 0; q < NQ; ++q) p[q * NU] = r[q];
  }
}

__global__ __launch_bounds__(256)
void lrsig_combine_kernel(const float* __restrict__ ws, float* __restrict__ out)
{
  const int gid = blockIdx.x * blockDim.x + threadIdx.x;   // 0..2047
  const int u = gid & 63;
  const int b = gid >> 6;
  float c1 = 0.f, c3 = 0.f, cA = 0.f, c6 = 0.f, cP = 0.f, cQ = 0.f, o = 0.f;
  for (int cc = 0; cc < NCC; ++cc) {
    const float* p = &ws[(((size_t)b * NCC + cc) * NQ) * NU + u];
    float q[NQ];
#pragma unroll
    for (int i = 0; i < NQ; ++i) q[i] = p[i * NU];
    o  += q[0] + q[1]*c1 + q[2]*c3 + q[3]*cA + q[4]*c6 + q[5]*cP + q[6]*cQ;
    cA += q[13]*c3 + q[9];             // uses c3_in
    cQ += q[15]*cP + q[16]*c6 + q[12]; // uses cP_in, c6_in
    cP += q[14]*c6 + q[11];            // uses c6_in
    c1 += q[7]; c3 += q[8]; c6 += q[10];
  }
  out[gid] = o;
}

extern "C" void kernel_launch(void* const* d_in, const int* in_sizes, int n_in,
                              void* d_out, int out_size, void* d_ws, size_t ws_size,
                              hipStream_t stream) {
  const float* X  = (const float*)d_in[0];   // (32, 2048, 63) fp32
  const float* Kw = (const float*)d_in[1];   // (64, 10, 64)   fp32
  float* out = (float*)d_out;                // (32, 64)       fp32
  float* ws  = (float*)d_ws;                 // 32*128*17*64*4 = 17.8 MB

  hipLaunchKernelGGL(lrsig_chunk_kernel, dim3(NCC, 32), dim3(128), 0, stream,
                     X, Kw, ws);
  hipLaunchKernelGGL(lrsig_combine_kernel, dim3(8), dim3(256), 0, stream,
                     ws, out);
}

// Round 3
// 148.330 us; speedup vs baseline: 1.2973x; 1.2973x over previous
//
#include <hip/hip_runtime.h>

// LowRankSig_HigherOrder: B=32, T=2048, F=64 (time + 63), K=10 tensors, U=64 units.
// Affine-scan decomposition (validated exact in round 1). Each wave (64 lanes =
// 64 units) handles a 16-row sub-chunk: computes the M-DIFF tile on the fly
// (fp32 dot products of dXa rows staged in LDS with kernel columns streamed
// from L2), scans with zero init state, and writes a 17-parameter affine map
// of the carried state (c1,c3,cA,c6,cP,cQ):
//   q0 o | q1..q6 a_* = d(out)/d(c_in) | q7..q12 d_* increments |
//   q13 tA3, q14 tP6, q15 tQP, q16 tQ6 couplings.
// A tiny second kernel folds the 128 maps sequentially per (b,u).
//
// Round-3 changes vs round 1 (166 us):
//  - LDS holds diffs (16 rows/wave) not raw rows (17): acc tile 17x4 -> 16x4,
//    drops ~20 VGPRs and the per-row subtractions.
//  - __launch_bounds__(256,4): cap VGPR at 128 -> 4 waves/SIMD, whole grid
//    (1024 WGs = 4/CU) resident. (Round 2's (128,5) caused scratch spills:
//    WRITE_SIZE 91 MB vs 17.8 MB of real writes -- do NOT over-demand.)
//  - one-f-ahead prefetch of kernel weights.

#define TT 2048
#define NFX 63
#define KT 10
#define NU 64
#define NQ 17
#define NCC 128      // 16-row sub-chunks per batch (ws layout)
#define TSTRIDE 68   // padded row stride (floats) for dXa [f][row], 64 rows

template<int KP>
__device__ __forceinline__ void compute_md(
    const float* __restrict__ Kw, const float* __restrict__ dXa,
    int rowbase, int u, int kbase, float (&acc)[16][KP])
{
#pragma unroll
  for (int r = 0; r < 16; ++r)
#pragma unroll
    for (int k = 0; k < KP; ++k) acc[r][k] = 0.f;

  const float* kp = &Kw[kbase * NU + u];
  float kvn[KP];
#pragma unroll
  for (int k = 0; k < KP; ++k) kvn[k] = kp[k * NU];

  for (int f = 0; f < 64; ++f) {
    float kv[KP];
#pragma unroll
    for (int k = 0; k < KP; ++k) kv[k] = kvn[k];
    kp += KT * NU;
    if (f < 63) {
#pragma unroll
      for (int k = 0; k < KP; ++k) kvn[k] = kp[k * NU];
    }
    const float* xb = &dXa[f * TSTRIDE + rowbase];
#pragma unroll
    for (int r4 = 0; r4 < 4; ++r4) {
      float4 v = *reinterpret_cast<const float4*>(xb + 4 * r4);
#pragma unroll
      for (int k = 0; k < KP; ++k) {
        acc[4*r4+0][k] = fmaf(v.x, kv[k], acc[4*r4+0][k]);
        acc[4*r4+1][k] = fmaf(v.y, kv[k], acc[4*r4+1][k]);
        acc[4*r4+2][k] = fmaf(v.z, kv[k], acc[4*r4+2][k]);
        acc[4*r4+3][k] = fmaf(v.w, kv[k], acc[4*r4+3][k]);
      }
    }
  }
}

__global__ __launch_bounds__(256, 4)
void lrsig_chunk_kernel(const float* __restrict__ X,
                        const float* __restrict__ Kw,
                        float* __restrict__ ws)
{
  __shared__ float dXa[64 * TSTRIDE];   // diff tile, transposed [f][row]

  const int b = blockIdx.y;
  const int c = blockIdx.x;          // 0..31, 64 rows per WG
  const int tid = threadIdx.x;
  const int u = tid & 63;
  const int w = tid >> 6;            // wave 0..3, rows [16w, 16w+16)
  const int t0 = c * 64;

  // ---- stage diff tile: dXa[f][r] = Xa[b,t0+r,f] - Xa[b,t0+r-1,f] (0 at t=0)
  for (int idx = tid; idx < 64 * NFX; idx += 256) {
    int row = idx / NFX;
    int col = idx - row * NFX;
    int gt = t0 + row;
    float d;
    if (gt == 0) d = 0.f;
    else {
      const float* px = &X[((size_t)b * TT + gt) * NFX + col];
      d = px[0] - px[-NFX];
    }
    dXa[(col + 1) * TSTRIDE + row] = d;
  }
  if (tid < 64) {
    dXa[tid] = (t0 + tid == 0) ? 0.f : (2.0f / 2047.0f);   // time feature f=0
  }
  __syncthreads();

  const int rowbase = 16 * w;
  float outq[NQ];

  // ---------- phase A: k = 0,1,2  (level-0 + m=1 chain) ----------
  {
    float acc[16][3];
    compute_md<3>(Kw, dXa, rowbase, u, 0, acc);
    float oA = 0.f, a1 = 0.f, lc1 = 0.f;
#pragma unroll
    for (int t = 0; t < 16; ++t) {
      float m0 = acc[t][0], m1 = acc[t][1], m2 = acc[t][2];
      oA += m0 + m2 * (lc1 + 0.5f * m1);
      a1 += m2;
      lc1 += m1;
    }
    outq[0] = oA; outq[1] = a1; outq[7] = lc1;
  }

  // ---------- phase B: k = 3,4,5  (m=2 chain) ----------
  {
    float acc[16][3];
    compute_md<3>(Kw, dXa, rowbase, u, 3, acc);
    float oB = 0.f, a3 = 0.f, aA = 0.f;
    float lc3 = 0.f, lcA = 0.f, g4 = 0.f;
#pragma unroll
    for (int t = 0; t < 16; ++t) {
      float m3 = acc[t][0], m4 = acc[t][1], m5 = acc[t][2];
      float s0 = m4 * lc3;
      float s1 = 0.5f * m4 * m3;
      oB += m5 * (lcA + 0.5f * s0 + (1.f/3.f) * s1);
      a3 += m5 * (g4 + 0.5f * m4);
      aA += m5;
      lcA += s0 + s1;
      g4  += m4;
      lc3 += m3;
    }
    outq[0] += oB;
    outq[2] = a3; outq[3] = aA; outq[8] = lc3; outq[9] = lcA; outq[13] = g4;
  }

  // ---------- phase C: k = 6,7,8,9  (m=3 chain) ----------
  {
    float acc[16][4];
    compute_md<4>(Kw, dXa, rowbase, u, 6, acc);
    float oC = 0.f, a6 = 0.f, aP = 0.f, aQ = 0.f;
    float lc6 = 0.f, lcP = 0.f, lcQ = 0.f, g7 = 0.f, g8 = 0.f, h = 0.f;
#pragma unroll
    for (int t = 0; t < 16; ++t) {
      float m6 = acc[t][0], m7 = acc[t][1], m8 = acc[t][2], m9 = acc[t][3];
      float p0 = m7 * lc6;
      float p1 = 0.5f * m7 * m6;
      float q0 = m8 * lcP;
      float q1 = 0.5f * m8 * p0;
      float q2 = (1.f/3.f) * m8 * p1;
      oC += m9 * (lcQ + 0.5f * q0 + (1.f/3.f) * q1 + 0.25f * q2);
      a6 += m9 * (h + m8 * (0.5f * g7 + (1.f/6.f) * m7));
      aP += m9 * (g8 + 0.5f * m8);
      aQ += m9;
      h  += m8 * (g7 + 0.5f * m7);   // exclusive g7, before update
      lcP += p0 + p1;
      lcQ += q0 + q1 + q2;
      g7 += m7; g8 += m8; lc6 += m6;
    }
    outq[0] += oC;
    outq[4] = a6; outq[5] = aP; outq[6] = aQ;
    outq[10] = lc6; outq[11] = lcP; outq[12] = lcQ;
    outq[14] = g7; outq[15] = g8; outq[16] = h;
  }

  // ---- write 17 scalars, coalesced over u ----
  const int cc = c * 4 + w;          // global sub-chunk index, time-ordered
  float* p = &ws[(((size_t)b * NCC + cc) * NQ) * NU + u];
#pragma unroll
  for (int q = 0; q < NQ; ++q) p[q * NU] = outq[q];
}

__global__ __launch_bounds__(256)
void lrsig_combine_kernel(const float* __restrict__ ws, float* __restrict__ out)
{
  const int gid = blockIdx.x * blockDim.x + threadIdx.x;   // 0..2047
  const int u = gid & 63;
  const int b = gid >> 6;
  float c1 = 0.f, c3 = 0.f, cA = 0.f, c6 = 0.f, cP = 0.f, cQ = 0.f, o = 0.f;
  for (int cc = 0; cc < NCC; ++cc) {
    const float* p = &ws[(((size_t)b * NCC + cc) * NQ) * NU + u];
    float q[NQ];
#pragma unroll
    for (int i = 0; i < NQ; ++i) q[i] = p[i * NU];
    o  += q[0] + q[1]*c1 + q[2]*c3 + q[3]*cA + q[4]*c6 + q[5]*cP + q[6]*cQ;
    cA += q[13]*c3 + q[9];             // uses c3_in
    cQ += q[15]*cP + q[16]*c6 + q[12]; // uses cP_in, c6_in
    cP += q[14]*c6 + q[11];            // uses c6_in
    c1 += q[7]; c3 += q[8]; c6 += q[10];
  }
  out[gid] = o;
}

extern "C" void kernel_launch(void* const* d_in, const int* in_sizes, int n_in,
                              void* d_out, int out_size, void* d_ws, size_t ws_size,
                              hipStream_t stream) {
  const float* X  = (const float*)d_in[0];   // (32, 2048, 63) fp32
  const float* Kw = (const float*)d_in[1];   // (64, 10, 64)   fp32
  float* out = (float*)d_out;                // (32, 64)       fp32
  float* ws  = (float*)d_ws;                 // 32*128*17*64*4 = 17.8 MB

  hipLaunchKernelGGL(lrsig_chunk_kernel, dim3(32, 32), dim3(256), 0, stream,
                     X, Kw, ws);
  hipLaunchKernelGGL(lrsig_combine_kernel, dim3(8), dim3(256), 0, stream,
                     ws, out);
}